// Round 9
// baseline (295.964 us; speedup 1.0000x reference)
//
#include <hip/hip_runtime.h>

// ---------------------------------------------------------------------------
// AttentionMulti: x[4,2048,1024] fp32 -> qkv -> 16-head attention (D=64,
// scale=0.5, key-mask) -> out proj.  Inputs/outputs fp32, mask int32.
// Internal compute in bf16 MFMA.
// ---------------------------------------------------------------------------

typedef __bf16 bf16;
typedef __attribute__((ext_vector_type(8))) __bf16 bf16x8;
typedef __attribute__((ext_vector_type(4))) float f32x4;

#define MFMA16(a, b, c) __builtin_amdgcn_mfma_f32_16x16x32_bf16(a, b, c, 0, 0, 0)
#define GLOAD_LDS(src, dst) __builtin_amdgcn_global_load_lds( \
    (const __attribute__((address_space(1))) void*)(src),     \
    (__attribute__((address_space(3))) void*)(dst), 16, 0, 0)
#define BAR() __builtin_amdgcn_s_barrier()
#define VMCNT(n) asm volatile("s_waitcnt vmcnt(" #n ")" ::: "memory")

// 0.5 * log2(e): folded into Q (w_qkv cols 0..1023 and b_qkv[0..1023])
#define QSCALE 0.72134752f

// ---------------------------------------------------------------------------
__global__ __launch_bounds__(256, 1) void cvt_f32_bf16(
    const float* __restrict__ in, bf16* __restrict__ out, int n4)
{
    int i = blockIdx.x * 256 + threadIdx.x;
    if (i >= n4) return;
    float4 v = *(const float4*)(in + (size_t)i * 4);
    union { ushort4 u; bf16 h[4]; } o;
    o.h[0] = (bf16)v.x; o.h[1] = (bf16)v.y; o.h[2] = (bf16)v.z; o.h[3] = (bf16)v.w;
    *(ushort4*)(out + (size_t)i * 4) = o.u;
}

// ---------------------------------------------------------------------------
// out[c][r] = in[r][c] * (c < scale_rows ? scale : 1)
// ---------------------------------------------------------------------------
__global__ __launch_bounds__(256, 1) void transpose_f32_bf16(
    const float* __restrict__ in, bf16* __restrict__ out, int R, int C,
    int scale_rows, float scale)
{
    __shared__ float s[64][65];
    const int t  = threadIdx.x;
    const int r0 = blockIdx.y * 64;
    const int c0 = blockIdx.x * 64;
    const int tr  = t >> 4;
    const int tc4 = (t & 15) * 4;
#pragma unroll
    for (int p = 0; p < 4; ++p) {
        int r = tr + p * 16;
        float4 v = *(const float4*)(in + (size_t)(r0 + r) * C + c0 + tc4);
        s[r][tc4 + 0] = v.x; s[r][tc4 + 1] = v.y;
        s[r][tc4 + 2] = v.z; s[r][tc4 + 3] = v.w;
    }
    __syncthreads();
    const int cw  = t >> 3;
    const int rw8 = (t & 7) * 8;
#pragma unroll
    for (int p = 0; p < 2; ++p) {
        int c = cw + p * 32;
        float f = (c0 + c) < scale_rows ? scale : 1.0f;
        union { uint4 v; bf16 h[8]; } u;
#pragma unroll
        for (int j = 0; j < 8; ++j) u.h[j] = (bf16)(s[rw8 + j][c] * f);
        *(uint4*)(out + (size_t)(c0 + c) * R + r0 + rw8) = u.v;
    }
}

// ---------------------------------------------------------------------------
// 256x256-tile m201-style GEMM: BK=64, 4 phases/K-tile, 2 barriers/phase,
// counted vmcnt(6), fragment-dedup'd reads, 512 thr / 8 waves (2Mx4N).
// C[M][N] = A[M][K] @ Bt[N][K]^T + bias[N]  (bias[n]*=qscale for n<qcols)
//  - Wave rows INTERLEAVED across staging halves: row = h*128+wr*64+f*16+..
//    so quadrant h reads staging half h for ALL waves (dead-half invariant).
//  - Dedup: p0 loads af(h0)+b0 (12 b128), p1 loads b1 (4), p2 reloads
//    af(h1) (8), p3 loads none -> 24 b128/K-tile/wave (round-2 bug: 48).
//  - Stage map per body T: p0:Ahi(T+1) p1:Bhi(T+1) p2:Alo(T+2) p3:Blo(T+2);
//    each target dead >=2 barriers before the stage issue.
//  - p0: stage THEN VMCNT(6) (= 3 newer half-tiles in flight) -> drains
//    exactly tile T's 4 halves; VMCNT(0) only in the last body.
//  - 2 barriers/phase around the setprio'd 16-MFMA quadrant cluster.
// ---------------------------------------------------------------------------
template <typename OutT>
__global__ __launch_bounds__(512, 2) void gemm256_kernel(
    const bf16* __restrict__ A, const bf16* __restrict__ Bt,
    const float* __restrict__ bias, OutT* __restrict__ C,
    int M, int N, int K, int qcols, float qscale, int nbx)
{
    __shared__ __align__(16) bf16 As[2][256 * 64];   // 64 KiB
    __shared__ __align__(16) bf16 Bs[2][256 * 64];   // 64 KiB

    const int t    = threadIdx.x;
    const int lane = t & 63;
    const int wave = t >> 6;
    const int wr   = wave >> 2;        // 0..1 (M, interleaved)
    const int wc   = wave & 3;         // 0..3 (N)
    const int l15  = lane & 15;
    const int g    = lane >> 4;

    // XCD super-tile mapping (nwg % 8 == 0, (nwg/8) % nbx == 0)
    const int nwg  = gridDim.x;
    const int per  = nwg >> 3;
    const int mper = per / nbx;
    const int wg   = blockIdx.x;
    const int xcd  = wg & 7;
    const int idx  = wg >> 3;
    const int m0   = (xcd * mper + idx % mper) * 256;
    const int n0   = (idx / mper) * 256;

    const int ntile = K >> 6;          // 16 for K=1024

    // staging: one 128x64 half = 512 thr x 2 x 16B, pre-swizzled source
    int srow[2], sblk[2];
#pragma unroll
    for (int r = 0; r < 2; ++r) {
        int s = t * 16 + r * 8192;
        srow[r] = s >> 7;
        int blk = (s >> 4) & 7;
        sblk[r] = blk ^ (srow[r] & 7);
    }
    const int ldst0 = t * 8;

    const bf16* Abase = A  + (size_t)m0 * K;
    const bf16* Bbase = Bt + (size_t)n0 * K;

    const f32x4 z = {0.f, 0.f, 0.f, 0.f};
    f32x4 acc[8][4];
#pragma unroll
    for (int i = 0; i < 8; ++i)
#pragma unroll
        for (int j = 0; j < 4; ++j) acc[i][j] = z;

    auto stageA = [&](int tile, int h) {
        if (tile >= ntile) return;
        bf16* dst = &As[tile & 1][h * 8192];
        const bf16* src = Abase + (size_t)(h * 128) * K + tile * 64;
#pragma unroll
        for (int r = 0; r < 2; ++r)
            GLOAD_LDS(src + (size_t)srow[r] * K + sblk[r] * 8,
                      dst + ldst0 + r * 4096);
    };
    auto stageB = [&](int tile, int h) {
        if (tile >= ntile) return;
        bf16* dst = &Bs[tile & 1][h * 8192];
        const bf16* src = Bbase + (size_t)(h * 128) * K + tile * 64;
#pragma unroll
        for (int r = 0; r < 2; ++r)
            GLOAD_LDS(src + (size_t)srow[r] * K + sblk[r] * 8,
                      dst + ldst0 + r * 4096);
    };

#define LOAD_AF(slot, h_)                                                     \
    _Pragma("unroll")                                                         \
    for (int f = 0; f < 4; ++f) {                                             \
        int row = (h_) * 128 + wr * 64 + f * 16 + l15;                        \
        _Pragma("unroll")                                                     \
        for (int ks = 0; ks < 2; ++ks)                                        \
            af[f][ks] = *(const bf16x8*)(&As[slot][row * 64 +                 \
                            (((ks * 4 + g) ^ (row & 7)) * 8)]);               \
    }
#define LOAD_BF(slot, ch_, dstv)                                              \
    _Pragma("unroll")                                                         \
    for (int cf = 0; cf < 2; ++cf) {                                          \
        int row = (ch_) * 128 + wc * 32 + cf * 16 + l15;                      \
        _Pragma("unroll")                                                     \
        for (int ks = 0; ks < 2; ++ks)                                        \
            dstv[cf][ks] = *(const bf16x8*)(&Bs[slot][row * 64 +              \
                            (((ks * 4 + g) ^ (row & 7)) * 8)]);               \
    }
#define MFMA_Q(bv, h_, ch_)                                                   \
    {                                                                         \
        __builtin_amdgcn_s_setprio(1);                                        \
        _Pragma("unroll")                                                     \
        for (int f = 0; f < 4; ++f)                                           \
            _Pragma("unroll")                                                 \
            for (int cf = 0; cf < 2; ++cf) {                                  \
                acc[(h_) * 4 + f][(ch_) * 2 + cf] = MFMA16(                   \
                    af[f][0], bv[cf][0], acc[(h_) * 4 + f][(ch_) * 2 + cf]);  \
                acc[(h_) * 4 + f][(ch_) * 2 + cf] = MFMA16(                   \
                    af[f][1], bv[cf][1], acc[(h_) * 4 + f][(ch_) * 2 + cf]);  \
            }                                                                 \
        __builtin_amdgcn_s_setprio(0);                                        \
    }

    // ---- prologue: tile0 all 4 halves + tile1 lo halves (12 loads) ----
    stageA(0, 0); stageB(0, 0); stageA(0, 1); stageB(0, 1);
    stageA(1, 0); stageB(1, 0);

    auto body = [&](int slot, int T) {
        bf16x8 af[4][2], b0[2][2], b1[2][2];
        // ---- p0: quadrant (h0,ch0); publish tile T ----
        stageA(T + 1, 1);
        if (T + 1 < ntile) { VMCNT(6); } else { VMCNT(0); }
        BAR();
        LOAD_AF(slot, 0);
        LOAD_BF(slot, 0, b0);
        MFMA_Q(b0, 0, 0);
        BAR();
        // ---- p1: quadrant (h0,ch1) ----
        LOAD_BF(slot, 1, b1);
        stageB(T + 1, 1);
        BAR();
        MFMA_Q(b1, 0, 1);
        BAR();
        // ---- p2: quadrant (h1,ch0) ----
        LOAD_AF(slot, 1);
        stageA(T + 2, 0);
        BAR();
        MFMA_Q(b0, 1, 0);
        BAR();
        // ---- p3: quadrant (h1,ch1) ----
        stageB(T + 2, 0);
        BAR();
        MFMA_Q(b1, 1, 1);
        BAR();
    };

    const int niter = ntile >> 1;
    for (int i = 0; i < niter; ++i) {
        body(0, 2 * i);
        body(1, 2 * i + 1);
    }

#undef LOAD_AF
#undef LOAD_BF
#undef MFMA_Q

    // ---- epilogue: bias + store ----
#pragma unroll
    for (int rf = 0; rf < 8; ++rf) {
        int hh = rf >> 2, f = rf & 3;
        int row = m0 + hh * 128 + wr * 64 + f * 16 + g * 4;
#pragma unroll
        for (int cfi = 0; cfi < 4; ++cfi) {
            int chh = cfi >> 1, cc = cfi & 1;
            int col = n0 + chh * 128 + wc * 32 + cc * 16 + l15;
            float bs = bias[col];
            if (col < qcols) bs *= qscale;
#pragma unroll
            for (int r = 0; r < 4; ++r) {
                float v = acc[rf][cfi][r] + bs;
                C[(size_t)(row + r) * N + col] = (OutT)v;
            }
        }
    }
}

// ---------------------------------------------------------------------------
// Global V transpose: qkvb V block [b,n][h,d] -> VtG[b][h][d][n]  (bf16)
// ---------------------------------------------------------------------------
__global__ __launch_bounds__(256, 1) void vtrans_kernel(
    const bf16* __restrict__ qkv, bf16* __restrict__ vtg)
{
    __shared__ float tile[64][65];
    const int t  = threadIdx.x;
    const int n0 = blockIdx.x * 64;
    const int bh = blockIdx.y;
    const int b  = bh >> 4, h = bh & 15;
    const bf16* src = qkv + (size_t)(b * 2048 + n0) * 3072 + 2048 + h * 64;
#pragma unroll
    for (int r = 0; r < 2; ++r) {
        int s = t + r * 256;
        int row = s >> 3, c8 = (s & 7) * 8;
        union { uint4 v; bf16 h8[8]; } u;
        u.v = *(const uint4*)(src + (size_t)row * 3072 + c8);
#pragma unroll
        for (int j = 0; j < 8; ++j) tile[row][c8 + j] = (float)u.h8[j];
    }
    __syncthreads();
    bf16* dst = vtg + (size_t)bh * (64 * 2048) + n0;
#pragma unroll
    for (int r = 0; r < 2; ++r) {
        int s = t + r * 256;
        int d = s >> 3, n8 = (s & 7) * 8;
        union { uint4 v; bf16 h8[8]; } o;
#pragma unroll
        for (int j = 0; j < 8; ++j) o.h8[j] = (bf16)tile[n8 + j][d];
        *(uint4*)(dst + (size_t)d * 2048 + n8) = o.v;
    }
}

// ---------------------------------------------------------------------------
// Attention v6b (round-6/8 known-good: ~99 us, MfmaUtil 32%).
// ---------------------------------------------------------------------------
__global__ __launch_bounds__(256, 3) void attn_kernel(
    const bf16* __restrict__ qkv, const bf16* __restrict__ vtg,
    const int* __restrict__ mask, bf16* __restrict__ O)
{
    __shared__ __align__(16) bf16 Ks[2][64 * 64];   // 16 KB [key][d]  xor-swz
    __shared__ __align__(16) bf16 Vt[2][64 * 64];   // 16 KB [d][key]  xor-swz
    __shared__ __align__(16) bf16 Ps[4][16 * 88];   // 11 KB per-wave P
    __shared__ __align__(16) float mneg[2048];      //  8 KB: 0 or -1e30

    const int t    = threadIdx.x;
    const int lane = t & 63;
    const int wave = t >> 6;
    const int l15  = lane & 15;
    const int g    = lane >> 4;

    const int bid = (blockIdx.x & 7) * 128 + (blockIdx.x >> 3);
    const int qt  = bid & 15;
    const int bh  = bid >> 4;
    const int h   = bh & 15;
    const int b   = bh >> 4;
    const int q0  = qt * 128 + wave * 16;           // tile0; tile1 = q0 + 64

    const int* mrow = mask + b * 2048;
    for (int i = t; i < 2048; i += 256)
        mneg[i] = mrow[i] ? 0.0f : -1e30f;

    const size_t RS = 3072;
    const bf16* qp0 = qkv + (size_t)(b * 2048 + q0 + l15) * RS + h * 64 + g * 8;
    const bf16* qp1 = qp0 + (size_t)64 * RS;
    bf16x8 aQ[2][2];
    aQ[0][0] = *(const bf16x8*)(qp0);
    aQ[0][1] = *(const bf16x8*)(qp0 + 32);
    aQ[1][0] = *(const bf16x8*)(qp1);
    aQ[1][1] = *(const bf16x8*)(qp1 + 32);

    const bf16* kbase = qkv + (size_t)(b * 2048) * RS + 1024 + h * 64;
    const bf16* vbase = vtg + (size_t)bh * (64 * 2048);

    const int e0 = t * 8;
    int srow[2], scol[2];
#pragma unroll
    for (int r = 0; r < 2; ++r) {
        int e   = e0 + r * 2048;
        int row = e >> 6;
        int cb  = (e >> 3) & 7;
        srow[r] = row;
        scol[r] = ((cb ^ (row & 7)) * 8);
    }

    const int rb0 = ((g)     ^ (l15 & 7)) * 8;
    const int rb1 = ((4 + g) ^ (l15 & 7)) * 8;

    const f32x4 z = {0.f, 0.f, 0.f, 0.f};
    f32x4 o0[4] = {z, z, z, z}, o1[4] = {z, z, z, z};
    f32x4 lacc0 = z, lacc1 = z;

    bf16x8 ones;
#pragma unroll
    for (int j = 0; j < 8; ++j) ones[j] = (bf16)1.0f;

#pragma unroll
    for (int r = 0; r < 2; ++r) {
        GLOAD_LDS(kbase + (size_t)srow[r] * RS + scol[r],   &Ks[0][e0 + r * 2048]);
        GLOAD_LDS(vbase + (size_t)srow[r] * 2048 + scol[r], &Vt[0][e0 + r * 2048]);
    }
    asm volatile("s_waitcnt vmcnt(0)" ::: "memory");
    __syncthreads();

    for (int i = 0; i < 32; ++i) {
        const int kc  = i * 64;
        const int buf = i & 1;

        if (i + 1 < 32) {
#pragma unroll
            for (int r = 0; r < 2; ++r) {
                GLOAD_LDS(kbase + (size_t)(kc + 64 + srow[r]) * RS + scol[r],
                          &Ks[buf ^ 1][e0 + r * 2048]);
                GLOAD_LDS(vbase + (size_t)srow[r] * 2048 + kc + 64 + scol[r],
                          &Vt[buf ^ 1][e0 + r * 2048]);
            }
        }

        // ---- mask quad per kt: D[row=key=kt*16+g*4+r][col=q] ----
        f32x4 mb4[4];
#pragma unroll
        for (int kt = 0; kt < 4; ++kt)
#pragma unroll
            for (int r = 0; r < 4; ++r)
                mb4[kt][r] = mneg[kc + kt * 16 + g * 4 + r];

        // ---- K fragments, shared by both q-tiles ----
        bf16x8 bk[4][2];
#pragma unroll
        for (int kt = 0; kt < 4; ++kt) {
            const bf16* kr = &Ks[buf][(kt * 16 + l15) * 64];
            bk[kt][0] = *(const bf16x8*)(kr + rb0);
            bk[kt][1] = *(const bf16x8*)(kr + rb1);
        }

        // ---- tile 0: S^T = mfma(K, Q) (mask in C-init), packed P store ----
        f32x4 S[4];
#pragma unroll
        for (int kt = 0; kt < 4; ++kt) {
            S[kt] = MFMA16(bk[kt][0], aQ[0][0], mb4[kt]);
            S[kt] = MFMA16(bk[kt][1], aQ[0][1], S[kt]);
        }
#pragma unroll
        for (int kt = 0; kt < 4; ++kt) {
            union { bf16 hh[4]; ushort4 u; } pk;
#pragma unroll
            for (int r = 0; r < 4; ++r)
                pk.hh[r] = (bf16)__builtin_amdgcn_exp2f(S[kt][r]);
            *(ushort4*)(&Ps[wave][l15 * 88 + kt * 16 + g * 4]) = pk.u;
        }
        asm volatile("s_waitcnt lgkmcnt(0)" ::: "memory");
        __builtin_amdgcn_sched_barrier(0);
        const bf16x8 aP00 = *(const bf16x8*)(&Ps[wave][l15 * 88 + g * 8]);
        const bf16x8 aP01 = *(const bf16x8*)(&Ps[wave][l15 * 88 + 32 + g * 8]);
        asm volatile("s_waitcnt lgkmcnt(0)" ::: "memory");  // aP0 in regs
        __builtin_amdgcn_sched_barrier(0);

        // ---- tile 1: S^T (reusing bk) ----
#pragma unroll
        for (int kt = 0; kt < 4; ++kt) {
            S[kt] = MFMA16(bk[kt][0], aQ[1][0], mb4[kt]);
            S[kt] = MFMA16(bk[kt][1], aQ[1][1], S[kt]);
        }

        // ---- V fragments, read ONCE, shared by both q-tiles ----
        bf16x8 bv[4][2];
#pragma unroll
        for (int dt = 0; dt < 4; ++dt) {
            const bf16* vr = &Vt[buf][(dt * 16 + l15) * 64];
            bv[dt][0] = *(const bf16x8*)(vr + rb0);
            bv[dt][1] = *(const bf16x8*)(vr + rb1);
        }

#pragma unroll
        for (int kt = 0; kt < 4; ++kt) {
            union { bf16 hh[4]; ushort4 u; } pk;
#pragma unroll
            for (int r = 0; r < 4; ++r)
                pk.hh[r] = (bf16)__builtin_amdgcn_exp2f(S[kt][r]);
            *(ushort4*)(&Ps[wave][l15 * 88 + kt * 16 + g * 4]) = pk.u;
        }

        // ---- tile 0 accumulate (overlaps tile-1 P roundtrip) ----
        lacc0 = MFMA16(aP00, ones, lacc0);
        lacc0 = MFMA16(aP01, ones, lacc0);
#pragma unroll
        for (int dt = 0; dt < 4; ++dt) {
            o0[dt] = MFMA16(aP00, bv[dt][0], o0[dt]);
            o0[dt] = MFMA16(aP01, bv[dt][1], o0[dt]);
        }
        asm volatile("s_waitcnt lgkmcnt(0)" ::: "memory");  // P1 committed
        __builtin_amdgcn_sched_barrier(0);
        const bf16x8 aP10 = *(const bf16x8*)(&Ps[wave][l15 * 88 + g * 8]);
        const bf16x8 aP11 = *(const bf16x8*)(&Ps[wave][l15 * 88 + 32 + g * 8]);

        // ---- tile 1 accumulate ----
        lacc1 = MFMA16(aP10, ones, lacc1);
        lacc1 = MFMA16(aP11, ones, lacc1);
#pragma unroll
        for (int dt = 0; dt < 4; ++dt) {
            o1[dt] = MFMA16(aP10, bv[dt][0], o1[dt]);
            o1[dt] = MFMA16(aP11, bv[dt][1], o1[dt]);
        }

        asm volatile("s_waitcnt vmcnt(0)" ::: "memory");  // prefetch landed
        __syncthreads();   // single barrier: buf^1 published, buf reads done
    }

    float inv0[4], inv1[4];
#pragma unroll
    for (int r = 0; r < 4; ++r) {
        inv0[r] = 1.0f / fmaxf(lacc0[r], 1e-30f);
        inv1[r] = 1.0f / fmaxf(lacc1[r], 1e-30f);
    }
#pragma unroll
    for (int nt = 0; nt < 4; ++nt) {
#pragma unroll
        for (int r = 0; r < 4; ++r) {
            int d = nt * 16 + l15;
            int row0 = q0 + g * 4 + r;
            O[(size_t)(b * 2048 + row0) * 1024 + h * 64 + d] = (bf16)(o0[nt][r] * inv0[r]);
            O[(size_t)(b * 2048 + row0 + 64) * 1024 + h * 64 + d] = (bf16)(o1[nt][r] * inv1[r]);
        }
    }
}

// ---------------------------------------------------------------------------
extern "C" void kernel_launch(void* const* d_in, const int* in_sizes, int n_in,
                              void* d_out, int out_size, void* d_ws, size_t ws_size,
                              hipStream_t stream)
{
    const float* x     = (const float*)d_in[0];
    const int*   mask  = (const int*)d_in[1];
    const float* w_qkv = (const float*)d_in[2];
    const float* b_qkv = (const float*)d_in[3];
    const float* w_out = (const float*)d_in[4];
    const float* b_out = (const float*)d_in[5];
    float* out = (float*)d_out;

    char* ws = (char*)d_ws;
    bf16* qkvb  = (bf16*)(ws);                 // 48 MiB: [8192][3072]
    bf16* Obuf  = (bf16*)(ws + 50331648);      // 16 MiB: [8192][1024]
    bf16* xb    = (bf16*)(ws + 67108864);      // 16 MiB: [8192][1024]
    bf16* wqkvT = (bf16*)(ws + 83886080);      //  6 MiB: [3072][1024]
    bf16* woutT = (bf16*)(ws + 90177536);      //  2 MiB: [1024][1024]
    // VtG aliases xb: xb's last reader is the qkv GEMM, vtrans runs after it.
    bf16* vtg   = xb;                          // 16 MiB: [64 bh][64 d][2048 n]

    cvt_f32_bf16<<<dim3(8192), 256, 0, stream>>>(x, xb, 2097152);
    transpose_f32_bf16<<<dim3(48, 16), 256, 0, stream>>>(w_qkv, wqkvT, 1024, 3072,
                                                         1024, QSCALE);
    transpose_f32_bf16<<<dim3(16, 16), 256, 0, stream>>>(w_out, woutT, 1024, 1024,
                                                         0, 1.0f);
    gemm256_kernel<bf16><<<dim3(384), 512, 0, stream>>>(
        xb, wqkvT, b_qkv, qkvb, 8192, 3072, 1024, 1024, QSCALE, 12);
    vtrans_kernel<<<dim3(32, 64), 256, 0, stream>>>(qkvb, vtg);
    attn_kernel<<<dim3(1024), 256, 0, stream>>>(qkvb, vtg, mask, Obuf);
    gemm256_kernel<float><<<dim3(128), 512, 0, stream>>>(
        Obuf, woutT, b_out, out, 8192, 1024, 1024, 0, 1.0f, 4);
}

// Round 10
// 277.048 us; speedup vs baseline: 1.0683x; 1.0683x over previous
//
#include <hip/hip_runtime.h>

// ---------------------------------------------------------------------------
// AttentionMulti: x[4,2048,1024] fp32 -> qkv -> 16-head attention (D=64,
// scale=0.5, key-mask) -> out proj.  Inputs/outputs fp32, mask int32.
// Internal compute in bf16 MFMA.
// ---------------------------------------------------------------------------

typedef __bf16 bf16;
typedef __attribute__((ext_vector_type(8))) __bf16 bf16x8;
typedef __attribute__((ext_vector_type(4))) float f32x4;

#define MFMA16(a, b, c) __builtin_amdgcn_mfma_f32_16x16x32_bf16(a, b, c, 0, 0, 0)
#define GLOAD_LDS(src, dst) __builtin_amdgcn_global_load_lds( \
    (const __attribute__((address_space(1))) void*)(src),     \
    (__attribute__((address_space(3))) void*)(dst), 16, 0, 0)
#define BAR() __builtin_amdgcn_s_barrier()
#define VMCNT(n) asm volatile("s_waitcnt vmcnt(" #n ")" ::: "memory")

// 0.5 * log2(e): folded into Q (w_qkv cols 0..1023 and b_qkv[0..1023])
#define QSCALE 0.72134752f

// ---------------------------------------------------------------------------
// Fused prologue: cvt x->bf16 (blocks 0..8191) || transpose w_qkv
// (blocks 8192..8959) || transpose w_out (blocks 8960..9215).
// The three jobs are independent; fusing them overlaps the small transpose
// grids with the cvt stream and removes 2 inter-kernel gaps (7->5 launches).
// ---------------------------------------------------------------------------
__device__ __forceinline__ void transpose_tile(
    const float* __restrict__ in, bf16* __restrict__ out, int R, int C,
    int scale_rows, float scale, int bx, int by, int t, float (*s)[65])
{
    const int r0 = by * 64;
    const int c0 = bx * 64;
    const int tr  = t >> 4;
    const int tc4 = (t & 15) * 4;
#pragma unroll
    for (int p = 0; p < 4; ++p) {
        int r = tr + p * 16;
        float4 v = *(const float4*)(in + (size_t)(r0 + r) * C + c0 + tc4);
        s[r][tc4 + 0] = v.x; s[r][tc4 + 1] = v.y;
        s[r][tc4 + 2] = v.z; s[r][tc4 + 3] = v.w;
    }
    __syncthreads();
    const int cw  = t >> 3;
    const int rw8 = (t & 7) * 8;
#pragma unroll
    for (int p = 0; p < 2; ++p) {
        int c = cw + p * 32;
        float f = (c0 + c) < scale_rows ? scale : 1.0f;
        union { uint4 v; bf16 h[8]; } u;
#pragma unroll
        for (int j = 0; j < 8; ++j) u.h[j] = (bf16)(s[rw8 + j][c] * f);
        *(uint4*)(out + (size_t)(c0 + c) * R + r0 + rw8) = u.v;
    }
}

__global__ __launch_bounds__(256, 1) void prep_kernel(
    const float* __restrict__ x, bf16* __restrict__ xb,
    const float* __restrict__ w_qkv, bf16* __restrict__ wqkvT,
    const float* __restrict__ w_out, bf16* __restrict__ woutT)
{
    __shared__ float s[64][65];
    const int t = threadIdx.x;
    int blk = blockIdx.x;
    if (blk < 8192) {
        // cvt f32 -> bf16, 4 elems/thread (2097152 float4 groups total)
        int i = blk * 256 + t;
        float4 v = *(const float4*)(x + (size_t)i * 4);
        union { ushort4 u; bf16 h[4]; } o;
        o.h[0] = (bf16)v.x; o.h[1] = (bf16)v.y;
        o.h[2] = (bf16)v.z; o.h[3] = (bf16)v.w;
        *(ushort4*)(xb + (size_t)i * 4) = o.u;
        return;
    }
    blk -= 8192;
    if (blk < 768) {
        transpose_tile(w_qkv, wqkvT, 1024, 3072, 1024, QSCALE,
                       blk % 48, blk / 48, t, s);
    } else {
        blk -= 768;
        transpose_tile(w_out, woutT, 1024, 1024, 0, 1.0f,
                       blk % 16, blk / 16, t, s);
    }
}

// ---------------------------------------------------------------------------
// 128x256-tile GEMM, BK=64, 3-slot LDS pipeline, 512 thr / 8 waves (2Mx4N).
// XCD super-tile mapping (round-8 known-good: exact-round grids 768/256,
// resident set ~4MB/XCD).  Two 256^2 schedule ports (r2/r9) both lost to
// this structure's exact CU-round grids -- do not revisit.
// ---------------------------------------------------------------------------
template <typename OutT>
__global__ __launch_bounds__(512, 2) void gemm128x256_kernel(
    const bf16* __restrict__ A, const bf16* __restrict__ Bt,
    const float* __restrict__ bias, OutT* __restrict__ C,
    int M, int N, int K, int qcols, float qscale, int nbx)
{
    __shared__ __align__(16) bf16 As[3 * 128 * 64];   // 48 KiB
    __shared__ __align__(16) bf16 Bs[3 * 256 * 64];   // 96 KiB

    const int t    = threadIdx.x;
    const int lane = t & 63;
    const int wave = t >> 6;
    const int wr   = wave >> 2;        // 0..1 (M)
    const int wc   = wave & 3;         // 0..3 (N)
    const int l15  = lane & 15;
    const int g    = lane >> 4;

    // XCD super-tile mapping (bijective; nwg % 8 == 0, (nwg/8) % nbx == 0)
    const int nwg  = gridDim.x;
    const int per  = nwg >> 3;
    const int mper = per / nbx;
    const int wg   = blockIdx.x;
    const int xcd  = wg & 7;
    const int idx  = wg >> 3;
    const int m0   = (xcd * mper + idx % mper) * 128;
    const int n0   = (idx / mper) * 256;

    const int ntile = K >> 6;          // 16 for K=1024

    int srow[2], sblk[2];
#pragma unroll
    for (int r = 0; r < 2; ++r) {
        int s = t * 16 + r * 8192;
        srow[r] = s >> 7;
        int blk = (s >> 4) & 7;
        sblk[r] = blk ^ (srow[r] & 7);
    }
    const int ldst0 = t * 8;

    const bf16* Abase = A  + (size_t)m0 * K;
    const bf16* Bbase = Bt + (size_t)n0 * K;

    const f32x4 z = {0.f, 0.f, 0.f, 0.f};
    f32x4 acc[4][4];
#pragma unroll
    for (int i = 0; i < 4; ++i)
#pragma unroll
        for (int j = 0; j < 4; ++j) acc[i][j] = z;

    auto stageA = [&](int tile, int slot) {
        if (tile >= ntile) return;
        bf16* dst = As + slot * 8192;
        const bf16* src = Abase + tile * 64;
#pragma unroll
        for (int r = 0; r < 2; ++r)
            GLOAD_LDS(src + (size_t)srow[r] * K + sblk[r] * 8,
                      dst + ldst0 + r * 4096);
    };
    auto stageBh = [&](int tile, int slot, int h) {
        if (tile >= ntile) return;
        bf16* dst = Bs + slot * 16384 + h * 8192;
        const bf16* src = Bbase + (size_t)(h * 128) * K + tile * 64;
#pragma unroll
        for (int r = 0; r < 2; ++r)
            GLOAD_LDS(src + (size_t)srow[r] * K + sblk[r] * 8,
                      dst + ldst0 + r * 4096);
    };

#define LOAD_AF(slot)                                                         \
    _Pragma("unroll")                                                         \
    for (int f = 0; f < 4; ++f) {                                             \
        int row = wr * 64 + f * 16 + l15;                                     \
        _Pragma("unroll")                                                     \
        for (int ks = 0; ks < 2; ++ks)                                        \
            af[f][ks] = *(const bf16x8*)(&As[(slot) * 8192 + row * 64 +       \
                            (((ks * 4 + g) ^ (row & 7)) * 8)]);               \
    }
#define LOAD_BF(slot, half, dstv)                                             \
    _Pragma("unroll")                                                         \
    for (int c2 = 0; c2 < 2; ++c2) {                                          \
        int row = wc * 64 + ((half) * 2 + c2) * 16 + l15;                     \
        _Pragma("unroll")                                                     \
        for (int ks = 0; ks < 2; ++ks)                                        \
            dstv[c2][ks] = *(const bf16x8*)(&Bs[(slot) * 16384 + row * 64 +   \
                            (((ks * 4 + g) ^ (row & 7)) * 8)]);               \
    }
#define MFMA_H(bv, half)                                                      \
    {                                                                         \
        __builtin_amdgcn_s_setprio(1);                                        \
        _Pragma("unroll")                                                     \
        for (int f = 0; f < 4; ++f)                                           \
            _Pragma("unroll")                                                 \
            for (int c2 = 0; c2 < 2; ++c2) {                                  \
                acc[f][(half) * 2 + c2] = MFMA16(                             \
                    af[f][0], bv[c2][0], acc[f][(half) * 2 + c2]);            \
                acc[f][(half) * 2 + c2] = MFMA16(                             \
                    af[f][1], bv[c2][1], acc[f][(half) * 2 + c2]);            \
            }                                                                 \
        __builtin_amdgcn_s_setprio(0);                                        \
    }

    // ---- prologue: tile0 -> slot0, tile1 -> slot1 (6 loads each) ----
    stageA(0, 0); stageBh(0, 0, 0); stageBh(0, 0, 1);
    stageA(1, 1); stageBh(1, 1, 0); stageBh(1, 1, 1);
    VMCNT(6);     // tile0 landed; tile1's 6 in flight
    BAR();

    int slot = 0;
    for (int T = 0; T < ntile; ++T) {
        int slot2 = slot + 2; if (slot2 >= 3) slot2 -= 3;
        bf16x8 af[4][2], blo[2][2], bhi[2][2];
        // ---- phase A: af x bf_lo ----
        LOAD_AF(slot);
        LOAD_BF(slot, 0, blo);
        stageA(T + 2, slot2);
        stageBh(T + 2, slot2, 0);
        MFMA_H(blo, 0);
        BAR();
        // ---- phase B: af x bf_hi + pub-wait for tile T+1 ----
        LOAD_BF(slot, 1, bhi);
        stageBh(T + 2, slot2, 1);
        MFMA_H(bhi, 1);
        if (T + 1 < ntile) {
            if (T + 2 < ntile) { VMCNT(6); } else { VMCNT(0); }
        }
        BAR();
        slot = (slot == 2) ? 0 : slot + 1;
    }

#undef LOAD_AF
#undef LOAD_BF
#undef MFMA_H

    // ---- epilogue: bias + store ----
#pragma unroll
    for (int f = 0; f < 4; ++f) {
        int row = m0 + wr * 64 + f * 16 + g * 4;
#pragma unroll
        for (int cf = 0; cf < 4; ++cf) {
            int col = n0 + wc * 64 + cf * 16 + l15;
            float bs = bias[col];
            if (col < qcols) bs *= qscale;
#pragma unroll
            for (int r = 0; r < 4; ++r) {
                float v = acc[f][cf][r] + bs;
                C[(size_t)(row + r) * N + col] = (OutT)v;
            }
        }
    }
}

// ---------------------------------------------------------------------------
// Global V transpose: qkvb V block [b,n][h,d] -> VtG[b][h][d][n]  (bf16)
// ---------------------------------------------------------------------------
__global__ __launch_bounds__(256, 1) void vtrans_kernel(
    const bf16* __restrict__ qkv, bf16* __restrict__ vtg)
{
    __shared__ float tile[64][65];
    const int t  = threadIdx.x;
    const int n0 = blockIdx.x * 64;
    const int bh = blockIdx.y;
    const int b  = bh >> 4, h = bh & 15;
    const bf16* src = qkv + (size_t)(b * 2048 + n0) * 3072 + 2048 + h * 64;
#pragma unroll
    for (int r = 0; r < 2; ++r) {
        int s = t + r * 256;
        int row = s >> 3, c8 = (s & 7) * 8;
        union { uint4 v; bf16 h8[8]; } u;
        u.v = *(const uint4*)(src + (size_t)row * 3072 + c8);
#pragma unroll
        for (int j = 0; j < 8; ++j) tile[row][c8 + j] = (float)u.h8[j];
    }
    __syncthreads();
    bf16* dst = vtg + (size_t)bh * (64 * 2048) + n0;
#pragma unroll
    for (int r = 0; r < 2; ++r) {
        int s = t + r * 256;
        int d = s >> 3, n8 = (s & 7) * 8;
        union { uint4 v; bf16 h8[8]; } o;
#pragma unroll
        for (int j = 0; j < 8; ++j) o.h8[j] = (bf16)tile[n8 + j][d];
        *(uint4*)(dst + (size_t)d * 2048 + n8) = o.v;
    }
}

// ---------------------------------------------------------------------------
// Attention v6b (round-6/8 known-good: ~99 us, MfmaUtil 33%).
// ---------------------------------------------------------------------------
__global__ __launch_bounds__(256, 3) void attn_kernel(
    const bf16* __restrict__ qkv, const bf16* __restrict__ vtg,
    const int* __restrict__ mask, bf16* __restrict__ O)
{
    __shared__ __align__(16) bf16 Ks[2][64 * 64];   // 16 KB [key][d]  xor-swz
    __shared__ __align__(16) bf16 Vt[2][64 * 64];   // 16 KB [d][key]  xor-swz
    __shared__ __align__(16) bf16 Ps[4][16 * 88];   // 11 KB per-wave P
    __shared__ __align__(16) float mneg[2048];      //  8 KB: 0 or -1e30

    const int t    = threadIdx.x;
    const int lane = t & 63;
    const int wave = t >> 6;
    const int l15  = lane & 15;
    const int g    = lane >> 4;

    const int bid = (blockIdx.x & 7) * 128 + (blockIdx.x >> 3);
    const int qt  = bid & 15;
    const int bh  = bid >> 4;
    const int h   = bh & 15;
    const int b   = bh >> 4;
    const int q0  = qt * 128 + wave * 16;           // tile0; tile1 = q0 + 64

    const int* mrow = mask + b * 2048;
    for (int i = t; i < 2048; i += 256)
        mneg[i] = mrow[i] ? 0.0f : -1e30f;

    const size_t RS = 3072;
    const bf16* qp0 = qkv + (size_t)(b * 2048 + q0 + l15) * RS + h * 64 + g * 8;
    const bf16* qp1 = qp0 + (size_t)64 * RS;
    bf16x8 aQ[2][2];
    aQ[0][0] = *(const bf16x8*)(qp0);
    aQ[0][1] = *(const bf16x8*)(qp0 + 32);
    aQ[1][0] = *(const bf16x8*)(qp1);
    aQ[1][1] = *(const bf16x8*)(qp1 + 32);

    const bf16* kbase = qkv + (size_t)(b * 2048) * RS + 1024 + h * 64;
    const bf16* vbase = vtg + (size_t)bh * (64 * 2048);

    const int e0 = t * 8;
    int srow[2], scol[2];
#pragma unroll
    for (int r = 0; r < 2; ++r) {
        int e   = e0 + r * 2048;
        int row = e >> 6;
        int cb  = (e >> 3) & 7;
        srow[r] = row;
        scol[r] = ((cb ^ (row & 7)) * 8);
    }

    const int rb0 = ((g)     ^ (l15 & 7)) * 8;
    const int rb1 = ((4 + g) ^ (l15 & 7)) * 8;

    const f32x4 z = {0.f, 0.f, 0.f, 0.f};
    f32x4 o0[4] = {z, z, z, z}, o1[4] = {z, z, z, z};
    f32x4 lacc0 = z, lacc1 = z;

    bf16x8 ones;
#pragma unroll
    for (int j = 0; j < 8; ++j) ones[j] = (bf16)1.0f;

#pragma unroll
    for (int r = 0; r < 2; ++r) {
        GLOAD_LDS(kbase + (size_t)srow[r] * RS + scol[r],   &Ks[0][e0 + r * 2048]);
        GLOAD_LDS(vbase + (size_t)srow[r] * 2048 + scol[r], &Vt[0][e0 + r * 2048]);
    }
    asm volatile("s_waitcnt vmcnt(0)" ::: "memory");
    __syncthreads();

    for (int i = 0; i < 32; ++i) {
        const int kc  = i * 64;
        const int buf = i & 1;

        if (i + 1 < 32) {
#pragma unroll
            for (int r = 0; r < 2; ++r) {
                GLOAD_LDS(kbase + (size_t)(kc + 64 + srow[r]) * RS + scol[r],
                          &Ks[buf ^ 1][e0 + r * 2048]);
                GLOAD_LDS(vbase + (size_t)srow[r] * 2048 + kc + 64 + scol[r],
                          &Vt[buf ^ 1][e0 + r * 2048]);
            }
        }

        // ---- mask quad per kt: D[row=key=kt*16+g*4+r][col=q] ----
        f32x4 mb4[4];
#pragma unroll
        for (int kt = 0; kt < 4; ++kt)
#pragma unroll
            for (int r = 0; r < 4; ++r)
                mb4[kt][r] = mneg[kc + kt * 16 + g * 4 + r];

        // ---- K fragments, shared by both q-tiles ----
        bf16x8 bk[4][2];
#pragma unroll
        for (int kt = 0; kt < 4; ++kt) {
            const bf16* kr = &Ks[buf][(kt * 16 + l15) * 64];
            bk[kt][0] = *(const bf16x8*)(kr + rb0);
            bk[kt][1] = *(const bf16x8*)(kr + rb1);
        }

        // ---- tile 0: S^T = mfma(K, Q) (mask in C-init), packed P store ----
        f32x4 S[4];
#pragma unroll
        for (int kt = 0; kt < 4; ++kt) {
            S[kt] = MFMA16(bk[kt][0], aQ[0][0], mb4[kt]);
            S[kt] = MFMA16(bk[kt][1], aQ[0][1], S[kt]);
        }
#pragma unroll
        for (int kt = 0; kt < 4; ++kt) {
            union { bf16 hh[4]; ushort4 u; } pk;
#pragma unroll
            for (int r = 0; r < 4; ++r)
                pk.hh[r] = (bf16)__builtin_amdgcn_exp2f(S[kt][r]);
            *(ushort4*)(&Ps[wave][l15 * 88 + kt * 16 + g * 4]) = pk.u;
        }
        asm volatile("s_waitcnt lgkmcnt(0)" ::: "memory");
        __builtin_amdgcn_sched_barrier(0);
        const bf16x8 aP00 = *(const bf16x8*)(&Ps[wave][l15 * 88 + g * 8]);
        const bf16x8 aP01 = *(const bf16x8*)(&Ps[wave][l15 * 88 + 32 + g * 8]);
        asm volatile("s_waitcnt lgkmcnt(0)" ::: "memory");  // aP0 in regs
        __builtin_amdgcn_sched_barrier(0);

        // ---- tile 1: S^T (reusing bk) ----
#pragma unroll
        for (int kt = 0; kt < 4; ++kt) {
            S[kt] = MFMA16(bk[kt][0], aQ[1][0], mb4[kt]);
            S[kt] = MFMA16(bk[kt][1], aQ[1][1], S[kt]);
        }

        // ---- V fragments, read ONCE, shared by both q-tiles ----
        bf16x8 bv[4][2];
#pragma unroll
        for (int dt = 0; dt < 4; ++dt) {
            const bf16* vr = &Vt[buf][(dt * 16 + l15) * 64];
            bv[dt][0] = *(const bf16x8*)(vr + rb0);
            bv[dt][1] = *(const bf16x8*)(vr + rb1);
        }

#pragma unroll
        for (int kt = 0; kt < 4; ++kt) {
            union { bf16 hh[4]; ushort4 u; } pk;
#pragma unroll
            for (int r = 0; r < 4; ++r)
                pk.hh[r] = (bf16)__builtin_amdgcn_exp2f(S[kt][r]);
            *(ushort4*)(&Ps[wave][l15 * 88 + kt * 16 + g * 4]) = pk.u;
        }

        // ---- tile 0 accumulate (overlaps tile-1 P roundtrip) ----
        lacc0 = MFMA16(aP00, ones, lacc0);
        lacc0 = MFMA16(aP01, ones, lacc0);
#pragma unroll
        for (int dt = 0; dt < 4; ++dt) {
            o0[dt] = MFMA16(aP00, bv[dt][0], o0[dt]);
            o0[dt] = MFMA16(aP01, bv[dt][1], o0[dt]);
        }
        asm volatile("s_waitcnt lgkmcnt(0)" ::: "memory");  // P1 committed
        __builtin_amdgcn_sched_barrier(0);
        const bf16x8 aP10 = *(const bf16x8*)(&Ps[wave][l15 * 88 + g * 8]);
        const bf16x8 aP11 = *(const bf16x8*)(&Ps[wave][l15 * 88 + 32 + g * 8]);

        // ---- tile 1 accumulate ----
        lacc1 = MFMA16(aP10, ones, lacc1);
        lacc1 = MFMA16(aP11, ones, lacc1);
#pragma unroll
        for (int dt = 0; dt < 4; ++dt) {
            o1[dt] = MFMA16(aP10, bv[dt][0], o1[dt]);
            o1[dt] = MFMA16(aP11, bv[dt][1], o1[dt]);
        }

        asm volatile("s_waitcnt vmcnt(0)" ::: "memory");  // prefetch landed
        __syncthreads();   // single barrier: buf^1 published, buf reads done
    }

    float inv0[4], inv1[4];
#pragma unroll
    for (int r = 0; r < 4; ++r) {
        inv0[r] = 1.0f / fmaxf(lacc0[r], 1e-30f);
        inv1[r] = 1.0f / fmaxf(lacc1[r], 1e-30f);
    }
#pragma unroll
    for (int nt = 0; nt < 4; ++nt) {
#pragma unroll
        for (int r = 0; r < 4; ++r) {
            int d = nt * 16 + l15;
            int row0 = q0 + g * 4 + r;
            O[(size_t)(b * 2048 + row0) * 1024 + h * 64 + d] = (bf16)(o0[nt][r] * inv0[r]);
            O[(size_t)(b * 2048 + row0 + 64) * 1024 + h * 64 + d] = (bf16)(o1[nt][r] * inv1[r]);
        }
    }
}

// ---------------------------------------------------------------------------
extern "C" void kernel_launch(void* const* d_in, const int* in_sizes, int n_in,
                              void* d_out, int out_size, void* d_ws, size_t ws_size,
                              hipStream_t stream)
{
    const float* x     = (const float*)d_in[0];
    const int*   mask  = (const int*)d_in[1];
    const float* w_qkv = (const float*)d_in[2];
    const float* b_qkv = (const float*)d_in[3];
    const float* w_out = (const float*)d_in[4];
    const float* b_out = (const float*)d_in[5];
    float* out = (float*)d_out;

    char* ws = (char*)d_ws;
    bf16* qkvb  = (bf16*)(ws);                 // 48 MiB: [8192][3072]
    bf16* Obuf  = (bf16*)(ws + 50331648);      // 16 MiB: [8192][1024]
    bf16* xb    = (bf16*)(ws + 67108864);      // 16 MiB: [8192][1024]
    bf16* wqkvT = (bf16*)(ws + 83886080);      //  6 MiB: [3072][1024]
    bf16* woutT = (bf16*)(ws + 90177536);      //  2 MiB: [1024][1024]
    // VtG aliases xb: xb's last reader is the qkv GEMM, vtrans runs after it.
    bf16* vtg   = xb;                          // 16 MiB: [64 bh][64 d][2048 n]

    prep_kernel<<<dim3(9216), 256, 0, stream>>>(x, xb, w_qkv, wqkvT, w_out, woutT);
    gemm128x256_kernel<bf16><<<dim3(768), 512, 0, stream>>>(
        xb, wqkvT, b_qkv, qkvb, 8192, 3072, 1024, 1024, QSCALE, 12);
    vtrans_kernel<<<dim3(32, 64), 256, 0, stream>>>(qkvb, vtg);
    attn_kernel<<<dim3(1024), 256, 0, stream>>>(qkvb, vtg, mask, Obuf);
    gemm128x256_kernel<float><<<dim3(256), 512, 0, stream>>>(
        Obuf, woutT, b_out, out, 8192, 1024, 1024, 0, 1.0f, 4);
}